// Round 1
// 258.162 us; speedup vs baseline: 1.0124x; 1.0124x over previous
//
#include <hip/hip_runtime.h>

#define IN_FEATS 256
#define OUT_FEATS 32
#define NUM_HEADS 4
#define NHF 128   // NUM_HEADS*OUT_FEATS

typedef __attribute__((ext_vector_type(8))) short short8;
typedef __attribute__((ext_vector_type(4))) float f32x4;

__device__ inline unsigned short f2bf(float f) {
    unsigned int u = __builtin_bit_cast(unsigned int, f);
    u = (u + 0x7fff + ((u >> 16) & 1)) >> 16;   // RNE
    return (unsigned short)u;
}
__device__ inline float bfhi2f(unsigned int packed_hi) {   // bits already in [31:16]
    return __builtin_bit_cast(float, packed_hi);
}

// prep: blocks 0..127 transpose W -> Wt bf16 [128][256]; block 128 computes
// v[k*4+h] = sum_f W[k*128 + h*32 + f] * attn_r[h*32 + f]
__global__ __launch_bounds__(256) void prep(const float* __restrict__ W,
                                            const float* __restrict__ attn_r,
                                            float* __restrict__ v,
                                            unsigned short* __restrict__ Wt) {
    if (blockIdx.x < 128) {
        int n = blockIdx.x;
        int k = threadIdx.x;
        Wt[n * 256 + k] = f2bf(W[(size_t)k * NHF + n]);
    } else {
        for (int p = threadIdx.x; p < IN_FEATS * NUM_HEADS; p += 256) {
            int k = p >> 2, h = p & 3;
            const float* wr = W + (size_t)k * NHF + h * OUT_FEATS;
            const float* ar = attn_r + h * OUT_FEATS;
            float s = 0.f;
            #pragma unroll
            for (int f = 0; f < OUT_FEATS; ++f) s += wr[f] * ar[f];
            v[p] = s;
        }
    }
}

// ft16 = bf16(A @ W), el fused. One wave per 16 rows, MFMA 16x16x32 bf16.
// Wt staged in LDS (XOR-swizzled 16B chunks); all A loads hoisted pre-loop.
__global__ __launch_bounds__(256) void gemm_el(const float* __restrict__ A,
                                               const unsigned short* __restrict__ Wt,
                                               const float* __restrict__ attn_l,
                                               unsigned short* __restrict__ ft16,
                                               float* __restrict__ el, int M) {
    __shared__ unsigned short WtL[128 * 256];   // 64 KB, chunk (c,n) at ((c+n)&31)

    const int wave = threadIdx.x >> 6;
    const int lane = threadIdx.x & 63;
    const int quad = lane >> 4;
    const int mc   = lane & 15;
    const int row_base = blockIdx.x * 64 + wave * 16;

    for (int i = threadIdx.x; i < 4096; i += 256) {
        const int n = i >> 5, c = i & 31;
        const int cs = (c + n) & 31;
        *(uint4*)(WtL + n * 256 + cs * 8) = *(const uint4*)(Wt + n * 256 + c * 8);
    }

    float al[8];
    #pragma unroll
    for (int t = 0; t < 8; ++t) al[t] = attn_l[(t >> 1) * 32 + (t & 1) * 16 + mc];

    const int rowA = min(row_base + mc, M - 1);
    const float* arow = A + (size_t)rowA * IN_FEATS;

    float4 a[8][2];
    #pragma unroll
    for (int kk = 0; kk < 8; ++kk) {
        a[kk][0] = *(const float4*)(arow + kk * 32 + quad * 8);
        a[kk][1] = *(const float4*)(arow + kk * 32 + quad * 8 + 4);
    }

    f32x4 acc[8];
    #pragma unroll
    for (int t = 0; t < 8; ++t) acc[t] = (f32x4){0.f, 0.f, 0.f, 0.f};

    __syncthreads();

    #pragma unroll
    for (int kk = 0; kk < 8; ++kk) {
        short8 af;
        af[0] = (short)f2bf(a[kk][0].x); af[1] = (short)f2bf(a[kk][0].y);
        af[2] = (short)f2bf(a[kk][0].z); af[3] = (short)f2bf(a[kk][0].w);
        af[4] = (short)f2bf(a[kk][1].x); af[5] = (short)f2bf(a[kk][1].y);
        af[6] = (short)f2bf(a[kk][1].z); af[7] = (short)f2bf(a[kk][1].w);
        #pragma unroll
        for (int t = 0; t < 8; ++t) {
            const int n = t * 16 + mc;
            const int c = ((kk << 2) + quad + n) & 31;
            const short8 bf = *(const short8*)(WtL + n * 256 + c * 8);
            acc[t] = __builtin_amdgcn_mfma_f32_16x16x32_bf16(af, bf, acc[t], 0, 0, 0);
        }
    }

    float elp[4][4];
    #pragma unroll
    for (int v = 0; v < 4; ++v)
        #pragma unroll
        for (int h = 0; h < 4; ++h) elp[v][h] = 0.f;
    #pragma unroll
    for (int v = 0; v < 4; ++v)
        #pragma unroll
        for (int t = 0; t < 8; ++t) elp[v][t >> 1] += acc[t][v] * al[t];
    #pragma unroll
    for (int v = 0; v < 4; ++v)
        #pragma unroll
        for (int h = 0; h < 4; ++h) {
            #pragma unroll
            for (int d = 1; d < 16; d <<= 1)
                elp[v][h] += __shfl_xor(elp[v][h], d, 64);
        }

    #pragma unroll
    for (int v = 0; v < 4; ++v) {
        const int rg = row_base + quad * 4 + v;
        if (rg < M) {
            unsigned short* o = ft16 + (size_t)rg * NHF;
            #pragma unroll
            for (int t = 0; t < 8; ++t) o[t * 16 + mc] = f2bf(acc[t][v]);
            if (mc < 4) {
                float ev = (mc == 0) ? elp[v][0] : (mc == 1) ? elp[v][1]
                         : (mc == 2) ? elp[v][2] : elp[v][3];
                el[(size_t)rg * 4 + mc] = ev;
            }
        }
    }
}

// er[n*4+h] = sum_k h_dst[n*256+k] * v[k*4+h]   (one wave per row)
__global__ __launch_bounds__(256) void compute_er(const float* __restrict__ hdst,
                                                  const float* __restrict__ v,
                                                  float* __restrict__ er, int M) {
    int wid  = (blockIdx.x * blockDim.x + threadIdx.x) >> 6;
    int lane = threadIdx.x & 63;
    if (wid >= M) return;
    const float4 x = *(const float4*)(hdst + (size_t)wid * IN_FEATS + lane * 4);
    const float4* vp = (const float4*)(v + (size_t)lane * 16);
    float4 v0 = vp[0], v1 = vp[1], v2 = vp[2], v3 = vp[3];
    float a0 = x.x * v0.x + x.y * v1.x + x.z * v2.x + x.w * v3.x;
    float a1 = x.x * v0.y + x.y * v1.y + x.z * v2.y + x.w * v3.y;
    float a2 = x.x * v0.z + x.y * v1.z + x.z * v2.z + x.w * v3.z;
    float a3 = x.x * v0.w + x.y * v1.w + x.z * v2.w + x.w * v3.w;
    #pragma unroll
    for (int m = 32; m >= 1; m >>= 1) {
        a0 += __shfl_xor(a0, m, 64);
        a1 += __shfl_xor(a1, m, 64);
        a2 += __shfl_xor(a2, m, 64);
        a3 += __shfl_xor(a3, m, 64);
    }
    if (lane == 0) *(float4*)(er + (size_t)wid * 4) = make_float4(a0, a1, a2, a3);
}

// ---- two-level counting sort by dst (bucket = dst>>8) ----

// coarse histogram, LDS-reduced
__global__ __launch_bounds__(256) void bucket_hist(const int* __restrict__ dst,
                                                   int* __restrict__ bcnt, int E) {
    __shared__ int h[256];
    h[threadIdx.x] = 0;
    __syncthreads();
    for (int e = blockIdx.x * 256 + threadIdx.x; e < E; e += gridDim.x * 256)
        atomicAdd(&h[dst[e] >> 8], 1);
    __syncthreads();
    int c = h[threadIdx.x];
    if (c) atomicAdd(&bcnt[threadIdx.x], c);
}

// 1 block: exclusive scan of 256 bucket counts -> bbase[257], bcursor; off[n]=E
__global__ __launch_bounds__(256) void bucket_scan(const int* __restrict__ bcnt,
                                                   int* __restrict__ bbase,
                                                   int* __restrict__ bcursor,
                                                   int* __restrict__ off, int n_dst, int E) {
    __shared__ int s[256];
    int t = threadIdx.x;
    int v = bcnt[t];
    s[t] = v;
    __syncthreads();
    #pragma unroll
    for (int d = 1; d < 256; d <<= 1) {
        int x = (t >= d) ? s[t - d] : 0;
        __syncthreads();
        s[t] += x;
        __syncthreads();
    }
    int ex = s[t] - v;
    bbase[t] = ex;
    bcursor[t] = ex;
    if (t == 255) bbase[256] = s[255];
    if (t == 0) off[n_dst] = E;
}

// per-chunk (4096 edges) binning: count, reserve contiguous runs, write pairs
__global__ __launch_bounds__(256) void bin_pairs(const int* __restrict__ src,
                                                 const int* __restrict__ dst,
                                                 int* __restrict__ bcursor,
                                                 int2* __restrict__ pairs, int E) {
    __shared__ int cnt[256];
    __shared__ int basel[256];
    const int e0 = blockIdx.x * 4096;
    const int e1 = min(e0 + 4096, E);
    const int t = threadIdx.x;
    cnt[t] = 0;
    __syncthreads();
    for (int e = e0 + t; e < e1; e += 256)
        atomicAdd(&cnt[dst[e] >> 8], 1);
    __syncthreads();
    int c = cnt[t];
    basel[t] = c ? atomicAdd(&bcursor[t], c) : 0;
    __syncthreads();
    cnt[t] = 0;
    __syncthreads();
    for (int e = e0 + t; e < e1; e += 256) {
        int d = dst[e];
        int b = d >> 8;
        int o = atomicAdd(&cnt[b], 1);
        pairs[basel[b] + o] = make_int2(src[e], d);
    }
}

// one block per bucket: exact CSR within the bucket's contiguous region
__global__ __launch_bounds__(256) void fine_csr(const int2* __restrict__ pairs,
                                                const int* __restrict__ bbase,
                                                int* __restrict__ off,
                                                int* __restrict__ csr_src, int n_dst) {
    __shared__ int cnt[256];
    __shared__ int cur[256];
    const int b = blockIdx.x;
    const int p0 = bbase[b], p1 = bbase[b + 1];
    const int t = threadIdx.x;
    cnt[t] = 0;
    __syncthreads();
    for (int p = p0 + t; p < p1; p += 256)
        atomicAdd(&cnt[pairs[p].y & 255], 1);
    __syncthreads();
    int v = cnt[t];
    cur[t] = v;
    __syncthreads();
    #pragma unroll
    for (int d = 1; d < 256; d <<= 1) {
        int x = (t >= d) ? cur[t - d] : 0;
        __syncthreads();
        cur[t] += x;
        __syncthreads();
    }
    int ex = cur[t] - v;
    int node = b * 256 + t;
    if (node < n_dst) off[node] = p0 + ex;
    __syncthreads();
    cur[t] = ex;
    __syncthreads();
    for (int p = p0 + t; p < p1; p += 256) {
        int2 pr = pairs[p];
        int o = atomicAdd(&cur[pr.y & 255], 1);
        csr_src[p0 + o] = pr.x;
    }
}

// TWO dst nodes per wave (32 lanes each; lane owns cols 4*hl..4*hl+3 via one
// uint2 load). Per half-wave: up to 32 csr entries preloaded with ONE coalesced
// load, broadcast via __shfl(width=32) -> no csr round trip per chunk.
// 2-stage software pipeline: next chunk's el/ft gathers issue before current
// chunk's math. Branchless clamped indices keep control flow wave-uniform.
__global__ __launch_bounds__(256) void agg_pull(const int* __restrict__ off,
                                                const int* __restrict__ csr_src,
                                                const float* __restrict__ el,
                                                const float* __restrict__ er,
                                                const uint2* __restrict__ ftp,
                                                float* __restrict__ out, int n_dst) {
    const int wid  = (blockIdx.x * blockDim.x + threadIdx.x) >> 6;
    const int lane = threadIdx.x & 63;
    const int half = lane >> 5;
    const int hl   = lane & 31;
    const int node = wid * 2 + half;
    const bool valid = node < n_dst;
    const int nc = valid ? node : 0;
    const int h  = hl >> 3;                       // head = (4*hl)/32
    const float er_h = er[nc * 4 + h];
    const int start = off[nc];
    const int end   = valid ? off[nc + 1] : start;
    const int deg   = end - start;
    const int last  = max(end - 1, 0);

    // one coalesced load: up to 32 csr entries for this half's node
    const int sl = csr_src[min(start + hl, last)];

    const int mdeg  = max(deg, __shfl_xor(deg, 32, 64));
    const int iters = (min(mdeg, 32) + 3) >> 2;

    float a0 = 0.f, a1 = 0.f, a2 = 0.f, a3 = 0.f, sw = 0.f;

    // prologue: issue chunk 0 gathers
    int s0 = __shfl(sl, 0, 32), s1 = __shfl(sl, 1, 32),
        s2 = __shfl(sl, 2, 32), s3 = __shfl(sl, 3, 32);
    float e0 = el[s0 * 4 + h], e1 = el[s1 * 4 + h],
          e2 = el[s2 * 4 + h], e3 = el[s3 * 4 + h];
    uint2 q0 = ftp[s0 * 32 + hl], q1 = ftp[s1 * 32 + hl],
          q2 = ftp[s2 * 32 + hl], q3 = ftp[s3 * 32 + hl];

    for (int i = 0; i < iters; ++i) {
        // issue NEXT chunk's gathers (clamped; harmless past the end)
        const int jn = (i + 1) << 2;
        const int t0 = __shfl(sl, min(jn,     31), 32);
        const int t1 = __shfl(sl, min(jn + 1, 31), 32);
        const int t2 = __shfl(sl, min(jn + 2, 31), 32);
        const int t3 = __shfl(sl, min(jn + 3, 31), 32);
        const float f0 = el[t0 * 4 + h], f1 = el[t1 * 4 + h],
                    f2 = el[t2 * 4 + h], f3 = el[t3 * 4 + h];
        const uint2 r0 = ftp[t0 * 32 + hl], r1 = ftp[t1 * 32 + hl],
                    r2 = ftp[t2 * 32 + hl], r3 = ftp[t3 * 32 + hl];

        // compute CURRENT chunk
        const int kb = start + (i << 2);
        float x0 = e0 + er_h, x1 = e1 + er_h, x2 = e2 + er_h, x3 = e3 + er_h;
        x0 = fmaxf(x0, 0.2f * x0);
        x1 = fmaxf(x1, 0.2f * x1);
        x2 = fmaxf(x2, 0.2f * x2);
        x3 = fmaxf(x3, 0.2f * x3);
        const float w0 = (kb     < end) ? __expf(x0) : 0.f;
        const float w1 = (kb + 1 < end) ? __expf(x1) : 0.f;
        const float w2 = (kb + 2 < end) ? __expf(x2) : 0.f;
        const float w3 = (kb + 3 < end) ? __expf(x3) : 0.f;
        sw += (w0 + w1) + (w2 + w3);
        a0 = fmaf(bfhi2f(q0.x << 16),          w0, a0);
        a1 = fmaf(bfhi2f(q0.x & 0xffff0000u),  w0, a1);
        a2 = fmaf(bfhi2f(q0.y << 16),          w0, a2);
        a3 = fmaf(bfhi2f(q0.y & 0xffff0000u),  w0, a3);
        a0 = fmaf(bfhi2f(q1.x << 16),          w1, a0);
        a1 = fmaf(bfhi2f(q1.x & 0xffff0000u),  w1, a1);
        a2 = fmaf(bfhi2f(q1.y << 16),          w1, a2);
        a3 = fmaf(bfhi2f(q1.y & 0xffff0000u),  w1, a3);
        a0 = fmaf(bfhi2f(q2.x << 16),          w2, a0);
        a1 = fmaf(bfhi2f(q2.x & 0xffff0000u),  w2, a1);
        a2 = fmaf(bfhi2f(q2.y << 16),          w2, a2);
        a3 = fmaf(bfhi2f(q2.y & 0xffff0000u),  w2, a3);
        a0 = fmaf(bfhi2f(q3.x << 16),          w3, a0);
        a1 = fmaf(bfhi2f(q3.x & 0xffff0000u),  w3, a1);
        a2 = fmaf(bfhi2f(q3.y << 16),          w3, a2);
        a3 = fmaf(bfhi2f(q3.y & 0xffff0000u),  w3, a3);

        // rotate pipeline registers
        e0 = f0; e1 = f1; e2 = f2; e3 = f3;
        q0 = r0; q1 = r1; q2 = r2; q3 = r3;
    }

    // rare tail: degree > 32 (direct loads, uniform within the half)
    for (int k = start + 32; k < end; ++k) {
        const int s = csr_src[k];
        float x = el[s * 4 + h] + er_h;
        x = fmaxf(x, 0.2f * x);
        const float w = __expf(x);
        const uint2 q = ftp[s * 32 + hl];
        sw += w;
        a0 = fmaf(bfhi2f(q.x << 16),         w, a0);
        a1 = fmaf(bfhi2f(q.x & 0xffff0000u), w, a1);
        a2 = fmaf(bfhi2f(q.y << 16),         w, a2);
        a3 = fmaf(bfhi2f(q.y & 0xffff0000u), w, a3);
    }

    if (valid) {
        const float inv = (deg > 0) ? 1.f / sw : 0.f;
        float4 r;
        r.x = a0 * inv; r.y = a1 * inv; r.z = a2 * inv; r.w = a3 * inv;
        *(float4*)(out + (size_t)node * NHF + hl * 4) = r;
    }
}

extern "C" void kernel_launch(void* const* d_in, const int* in_sizes, int n_in,
                              void* d_out, int out_size, void* d_ws, size_t ws_size,
                              hipStream_t stream) {
    const float* h_src  = (const float*)d_in[0];
    const float* h_dst  = (const float*)d_in[1];
    const float* W      = (const float*)d_in[2];
    const float* attn_l = (const float*)d_in[3];
    const float* attn_r = (const float*)d_in[4];
    const int* src_idx  = (const int*)d_in[5];
    const int* dst_idx  = (const int*)d_in[6];

    const int n_src = in_sizes[0] / IN_FEATS;   // 50000
    const int n_dst = in_sizes[1] / IN_FEATS;   // 50000
    const int E     = in_sizes[5];              // 800000

    const int nbuck = (n_dst + 255) >> 8;       // 196 (<=256)

    // workspace layout
    char* ws = (char*)d_ws;
    size_t o = 0;
    float* v       = (float*)(ws + o); o += 4096;
    float* el      = (float*)(ws + o); o += (size_t)n_src * 4 * sizeof(float);
    float* er      = (float*)(ws + o); o += (size_t)n_dst * 4 * sizeof(float);
    int*   off     = (int*)(ws + o);   o += ((size_t)n_dst + 16) * sizeof(int);
    int*   bcnt    = (int*)(ws + o);   o += 256 * sizeof(int);
    int*   bbase   = (int*)(ws + o);   o += 260 * sizeof(int);
    int*   bcursor = (int*)(ws + o);   o += 256 * sizeof(int);
    unsigned short* Wt = (unsigned short*)(ws + o); o += (size_t)NHF * IN_FEATS * sizeof(unsigned short);
    int*   csr_src = (int*)(ws + o);   o += (size_t)E * sizeof(int);
    int2*  pairs   = (int2*)(ws + o);  o += (size_t)E * sizeof(int2);
    unsigned short* ft16 = (unsigned short*)(ws + o); o += (size_t)n_src * NHF * sizeof(unsigned short);

    float* out = (float*)d_out;

    (void)hipMemsetAsync(bcnt, 0, 256 * sizeof(int), stream);

    prep<<<129, 256, 0, stream>>>(W, attn_r, v, Wt);
    gemm_el<<<(n_src + 63) / 64, 256, 0, stream>>>(h_src, Wt, attn_l, ft16, el, n_src);
    compute_er<<<(n_dst + 3) / 4, 256, 0, stream>>>(h_dst, v, er, n_dst);
    bucket_hist<<<512, 256, 0, stream>>>(dst_idx, bcnt, E);
    bucket_scan<<<1, 256, 0, stream>>>(bcnt, bbase, bcursor, off, n_dst, E);
    bin_pairs<<<(E + 4095) / 4096, 256, 0, stream>>>(src_idx, dst_idx, bcursor, pairs, E);
    fine_csr<<<nbuck, 256, 0, stream>>>(pairs, bbase, off, csr_src, n_dst);
    {
        const int nwave = (n_dst + 1) >> 1;          // 2 nodes per wave
        agg_pull<<<(nwave + 3) / 4, 256, 0, stream>>>(off, csr_src, el, er,
                                                      (const uint2*)ft16, out, n_dst);
    }
}

// Round 2
// 254.980 us; speedup vs baseline: 1.0251x; 1.0125x over previous
//
#include <hip/hip_runtime.h>

#define IN_FEATS 256
#define OUT_FEATS 32
#define NUM_HEADS 4
#define NHF 128   // NUM_HEADS*OUT_FEATS

typedef __attribute__((ext_vector_type(8))) short short8;
typedef __attribute__((ext_vector_type(4))) float f32x4;

__device__ inline unsigned short f2bf(float f) {
    unsigned int u = __builtin_bit_cast(unsigned int, f);
    u = (u + 0x7fff + ((u >> 16) & 1)) >> 16;   // RNE
    return (unsigned short)u;
}
__device__ inline float bfhi2f(unsigned int packed_hi) {   // bits already in [31:16]
    return __builtin_bit_cast(float, packed_hi);
}

// prep: blocks 0..127 transpose W -> Wt bf16 [128][256]; block 128 computes
// v[k*4+h] = sum_f W[k*128 + h*32 + f] * attn_r[h*32 + f], and zeroes bcnt.
__global__ __launch_bounds__(256) void prep(const float* __restrict__ W,
                                            const float* __restrict__ attn_r,
                                            float* __restrict__ v,
                                            unsigned short* __restrict__ Wt,
                                            int* __restrict__ bcnt) {
    if (blockIdx.x < 128) {
        int n = blockIdx.x;
        int k = threadIdx.x;
        Wt[n * 256 + k] = f2bf(W[(size_t)k * NHF + n]);
    } else {
        bcnt[threadIdx.x] = 0;
        for (int p = threadIdx.x; p < IN_FEATS * NUM_HEADS; p += 256) {
            int k = p >> 2, h = p & 3;
            const float* wr = W + (size_t)k * NHF + h * OUT_FEATS;
            const float* ar = attn_r + h * OUT_FEATS;
            float s = 0.f;
            #pragma unroll
            for (int f = 0; f < OUT_FEATS; ++f) s += wr[f] * ar[f];
            v[p] = s;
        }
    }
}

// ft16 = bf16(A @ W), el fused. One wave per 16 rows, MFMA 16x16x32 bf16.
// Wt staged in LDS (XOR-swizzled 16B chunks); all A loads hoisted pre-loop.
// Epilogue: acc -> LDS bounce (reusing WtL) -> coalesced uint4 stores.
#define BSTRIDE 136   // bf16 elems; 272 B rows: 16B-aligned, 4-bank shift/row
__global__ __launch_bounds__(256) void gemm_el(const float* __restrict__ A,
                                               const unsigned short* __restrict__ Wt,
                                               const float* __restrict__ attn_l,
                                               unsigned short* __restrict__ ft16,
                                               float* __restrict__ el, int M) {
    __shared__ unsigned short WtL[128 * 256];   // 64 KB, chunk (c,n) at ((c+n)&31)

    const int wave = threadIdx.x >> 6;
    const int lane = threadIdx.x & 63;
    const int quad = lane >> 4;
    const int mc   = lane & 15;
    const int row_base = blockIdx.x * 64 + wave * 16;

    for (int i = threadIdx.x; i < 4096; i += 256) {
        const int n = i >> 5, c = i & 31;
        const int cs = (c + n) & 31;
        *(uint4*)(WtL + n * 256 + cs * 8) = *(const uint4*)(Wt + n * 256 + c * 8);
    }

    float al[8];
    #pragma unroll
    for (int t = 0; t < 8; ++t) al[t] = attn_l[(t >> 1) * 32 + (t & 1) * 16 + mc];

    const int rowA = min(row_base + mc, M - 1);
    const float* arow = A + (size_t)rowA * IN_FEATS;

    float4 a[8][2];
    #pragma unroll
    for (int kk = 0; kk < 8; ++kk) {
        a[kk][0] = *(const float4*)(arow + kk * 32 + quad * 8);
        a[kk][1] = *(const float4*)(arow + kk * 32 + quad * 8 + 4);
    }

    f32x4 acc[8];
    #pragma unroll
    for (int t = 0; t < 8; ++t) acc[t] = (f32x4){0.f, 0.f, 0.f, 0.f};

    __syncthreads();

    #pragma unroll
    for (int kk = 0; kk < 8; ++kk) {
        short8 af;
        af[0] = (short)f2bf(a[kk][0].x); af[1] = (short)f2bf(a[kk][0].y);
        af[2] = (short)f2bf(a[kk][0].z); af[3] = (short)f2bf(a[kk][0].w);
        af[4] = (short)f2bf(a[kk][1].x); af[5] = (short)f2bf(a[kk][1].y);
        af[6] = (short)f2bf(a[kk][1].z); af[7] = (short)f2bf(a[kk][1].w);
        #pragma unroll
        for (int t = 0; t < 8; ++t) {
            const int n = t * 16 + mc;
            const int c = ((kk << 2) + quad + n) & 31;
            const short8 bf = *(const short8*)(WtL + n * 256 + c * 8);
            acc[t] = __builtin_amdgcn_mfma_f32_16x16x32_bf16(af, bf, acc[t], 0, 0, 0);
        }
    }

    float elp[4][4];
    #pragma unroll
    for (int v = 0; v < 4; ++v)
        #pragma unroll
        for (int h = 0; h < 4; ++h) elp[v][h] = 0.f;
    #pragma unroll
    for (int v = 0; v < 4; ++v)
        #pragma unroll
        for (int t = 0; t < 8; ++t) elp[v][t >> 1] += acc[t][v] * al[t];
    #pragma unroll
    for (int v = 0; v < 4; ++v)
        #pragma unroll
        for (int h = 0; h < 4; ++h) {
            #pragma unroll
            for (int d = 1; d < 16; d <<= 1)
                elp[v][h] += __shfl_xor(elp[v][h], d, 64);
        }

    // el store (registers only, before LDS reuse)
    #pragma unroll
    for (int v = 0; v < 4; ++v) {
        const int rg = row_base + quad * 4 + v;
        if (rg < M && mc < 4) {
            float ev = (mc == 0) ? elp[v][0] : (mc == 1) ? elp[v][1]
                     : (mc == 2) ? elp[v][2] : elp[v][3];
            el[(size_t)rg * 4 + mc] = ev;
        }
    }

    __syncthreads();   // all waves done reading WtL -> safe to reuse as bounce
    #pragma unroll
    for (int v = 0; v < 4; ++v) {
        const int lr = wave * 16 + quad * 4 + v;
        #pragma unroll
        for (int t = 0; t < 8; ++t)
            WtL[lr * BSTRIDE + t * 16 + mc] = f2bf(acc[t][v]);
    }
    __syncthreads();
    const int rows_in_blk = min(64, M - blockIdx.x * 64);
    for (int i = threadIdx.x; i < 64 * 16; i += 256) {   // 16B segs
        const int lr = i >> 4, seg = i & 15;
        if (lr < rows_in_blk)
            *(uint4*)(ft16 + (size_t)(blockIdx.x * 64 + lr) * NHF + seg * 8) =
                *(const uint4*)(WtL + lr * BSTRIDE + seg * 8);
    }
}

// er[n*4+h] = sum_k h_dst[n*256+k] * v[k*4+h]   (one wave per row)
__global__ __launch_bounds__(256) void compute_er(const float* __restrict__ hdst,
                                                  const float* __restrict__ v,
                                                  float* __restrict__ er, int M) {
    int wid  = (blockIdx.x * blockDim.x + threadIdx.x) >> 6;
    int lane = threadIdx.x & 63;
    if (wid >= M) return;
    const float4 x = *(const float4*)(hdst + (size_t)wid * IN_FEATS + lane * 4);
    const float4* vp = (const float4*)(v + (size_t)lane * 16);
    float4 v0 = vp[0], v1 = vp[1], v2 = vp[2], v3 = vp[3];
    float a0 = x.x * v0.x + x.y * v1.x + x.z * v2.x + x.w * v3.x;
    float a1 = x.x * v0.y + x.y * v1.y + x.z * v2.y + x.w * v3.y;
    float a2 = x.x * v0.z + x.y * v1.z + x.z * v2.z + x.w * v3.z;
    float a3 = x.x * v0.w + x.y * v1.w + x.z * v2.w + x.w * v3.w;
    #pragma unroll
    for (int m = 32; m >= 1; m >>= 1) {
        a0 += __shfl_xor(a0, m, 64);
        a1 += __shfl_xor(a1, m, 64);
        a2 += __shfl_xor(a2, m, 64);
        a3 += __shfl_xor(a3, m, 64);
    }
    if (lane == 0) *(float4*)(er + (size_t)wid * 4) = make_float4(a0, a1, a2, a3);
}

// ---- two-level counting sort by dst (bucket = dst>>8) ----
// pairs packed: src (16 bits, n_src<65536) | (dst&255)<<16

// coarse histogram, LDS-reduced
__global__ __launch_bounds__(256) void bucket_hist(const int* __restrict__ dst,
                                                   int* __restrict__ bcnt, int E) {
    __shared__ int h[256];
    h[threadIdx.x] = 0;
    __syncthreads();
    for (int e = blockIdx.x * 256 + threadIdx.x; e < E; e += gridDim.x * 256)
        atomicAdd(&h[dst[e] >> 8], 1);
    __syncthreads();
    int c = h[threadIdx.x];
    if (c) atomicAdd(&bcnt[threadIdx.x], c);
}

// 1 block: exclusive scan of 256 bucket counts -> bbase[257], bcursor; off[n]=E
__global__ __launch_bounds__(256) void bucket_scan(const int* __restrict__ bcnt,
                                                   int* __restrict__ bbase,
                                                   int* __restrict__ bcursor,
                                                   int* __restrict__ off, int n_dst, int E) {
    __shared__ int s[256];
    int t = threadIdx.x;
    int v = bcnt[t];
    s[t] = v;
    __syncthreads();
    #pragma unroll
    for (int d = 1; d < 256; d <<= 1) {
        int x = (t >= d) ? s[t - d] : 0;
        __syncthreads();
        s[t] += x;
        __syncthreads();
    }
    int ex = s[t] - v;
    bbase[t] = ex;
    bcursor[t] = ex;
    if (t == 255) bbase[256] = s[255];
    if (t == 0) off[n_dst] = E;
}

// per-chunk (4096 edges) binning: count, reserve contiguous runs, write packed pairs
__global__ __launch_bounds__(256) void bin_pairs(const int* __restrict__ src,
                                                 const int* __restrict__ dst,
                                                 int* __restrict__ bcursor,
                                                 unsigned int* __restrict__ pairs, int E) {
    __shared__ int cnt[256];
    __shared__ int basel[256];
    const int e0 = blockIdx.x * 4096;
    const int e1 = min(e0 + 4096, E);
    const int t = threadIdx.x;
    cnt[t] = 0;
    __syncthreads();
    for (int e = e0 + t; e < e1; e += 256)
        atomicAdd(&cnt[dst[e] >> 8], 1);
    __syncthreads();
    int c = cnt[t];
    basel[t] = c ? atomicAdd(&bcursor[t], c) : 0;
    __syncthreads();
    cnt[t] = 0;
    __syncthreads();
    for (int e = e0 + t; e < e1; e += 256) {
        int d = dst[e];
        int b = d >> 8;
        int o = atomicAdd(&cnt[b], 1);
        pairs[basel[b] + o] = (unsigned int)src[e] | ((unsigned int)(d & 255) << 16);
    }
}

// one block per bucket: exact CSR within the bucket's contiguous region
__global__ __launch_bounds__(256) void fine_csr(const unsigned int* __restrict__ pairs,
                                                const int* __restrict__ bbase,
                                                int* __restrict__ off,
                                                int* __restrict__ csr_src, int n_dst) {
    __shared__ int cnt[256];
    __shared__ int cur[256];
    const int b = blockIdx.x;
    const int p0 = bbase[b], p1 = bbase[b + 1];
    const int t = threadIdx.x;
    cnt[t] = 0;
    __syncthreads();
    for (int p = p0 + t; p < p1; p += 256)
        atomicAdd(&cnt[pairs[p] >> 16], 1);
    __syncthreads();
    int v = cnt[t];
    cur[t] = v;
    __syncthreads();
    #pragma unroll
    for (int d = 1; d < 256; d <<= 1) {
        int x = (t >= d) ? cur[t - d] : 0;
        __syncthreads();
        cur[t] += x;
        __syncthreads();
    }
    int ex = cur[t] - v;
    int node = b * 256 + t;
    if (node < n_dst) off[node] = p0 + ex;
    __syncthreads();
    cur[t] = ex;
    __syncthreads();
    for (int p = p0 + t; p < p1; p += 256) {
        unsigned int pr = pairs[p];
        int o = atomicAdd(&cur[pr >> 16], 1);
        csr_src[p0 + o] = (int)(pr & 0xffffu);
    }
}

// TWO dst nodes per wave (32 lanes each; lane owns cols 4*hl..4*hl+3).
// Per half-wave: up to 32 csr entries preloaded with ONE coalesced load,
// broadcast via __shfl(width=32). 8-edge chunks, 2-stage software pipeline:
// next chunk's 8 el + 8 ft gathers issue before current chunk's math.
__global__ __launch_bounds__(256) void agg_pull(const int* __restrict__ off,
                                                const int* __restrict__ csr_src,
                                                const float* __restrict__ el,
                                                const float* __restrict__ er,
                                                const uint2* __restrict__ ftp,
                                                float* __restrict__ out, int n_dst) {
    const int wid  = (blockIdx.x * blockDim.x + threadIdx.x) >> 6;
    const int lane = threadIdx.x & 63;
    const int half = lane >> 5;
    const int hl   = lane & 31;
    const int node = wid * 2 + half;
    const bool valid = node < n_dst;
    const int nc = valid ? node : 0;
    const int h  = hl >> 3;                       // head = (4*hl)/32
    const float er_h = er[nc * 4 + h];
    const int start = off[nc];
    const int end   = valid ? off[nc + 1] : start;
    const int deg   = end - start;
    const int last  = max(end - 1, 0);

    // one coalesced load: up to 32 csr entries for this half's node
    const int sl = csr_src[min(start + hl, last)];

    const int mdeg  = max(deg, __shfl_xor(deg, 32, 64));
    const int iters = (min(mdeg, 32) + 7) >> 3;

    float a0 = 0.f, a1 = 0.f, a2 = 0.f, a3 = 0.f, sw = 0.f;

    float e[8]; uint2 q[8];
    #pragma unroll
    for (int j = 0; j < 8; ++j) {
        const int s = __shfl(sl, j, 32);
        e[j] = el[s * 4 + h];
        q[j] = ftp[s * 32 + hl];
    }

    for (int i = 0; i < iters; ++i) {
        // issue NEXT chunk's gathers (clamped; harmless past the end)
        float f[8]; uint2 r[8];
        const int jn = (i + 1) << 3;
        #pragma unroll
        for (int j = 0; j < 8; ++j) {
            const int s = __shfl(sl, min(jn + j, 31), 32);
            f[j] = el[s * 4 + h];
            r[j] = ftp[s * 32 + hl];
        }

        // compute CURRENT chunk
        const int kb = start + (i << 3);
        #pragma unroll
        for (int j = 0; j < 8; ++j) {
            float x = e[j] + er_h;
            x = fmaxf(x, 0.2f * x);
            const float w = (kb + j < end) ? __expf(x) : 0.f;
            sw += w;
            a0 = fmaf(bfhi2f(q[j].x << 16),          w, a0);
            a1 = fmaf(bfhi2f(q[j].x & 0xffff0000u),  w, a1);
            a2 = fmaf(bfhi2f(q[j].y << 16),          w, a2);
            a3 = fmaf(bfhi2f(q[j].y & 0xffff0000u),  w, a3);
        }

        #pragma unroll
        for (int j = 0; j < 8; ++j) { e[j] = f[j]; q[j] = r[j]; }
    }

    // rare tail: degree > 32 (direct loads, uniform within the half)
    for (int k = start + 32; k < end; ++k) {
        const int s = csr_src[k];
        float x = el[s * 4 + h] + er_h;
        x = fmaxf(x, 0.2f * x);
        const float w = __expf(x);
        const uint2 qq = ftp[s * 32 + hl];
        sw += w;
        a0 = fmaf(bfhi2f(qq.x << 16),         w, a0);
        a1 = fmaf(bfhi2f(qq.x & 0xffff0000u), w, a1);
        a2 = fmaf(bfhi2f(qq.y << 16),         w, a2);
        a3 = fmaf(bfhi2f(qq.y & 0xffff0000u), w, a3);
    }

    if (valid) {
        const float inv = (deg > 0) ? 1.f / sw : 0.f;
        float4 r;
        r.x = a0 * inv; r.y = a1 * inv; r.z = a2 * inv; r.w = a3 * inv;
        *(float4*)(out + (size_t)node * NHF + hl * 4) = r;
    }
}

extern "C" void kernel_launch(void* const* d_in, const int* in_sizes, int n_in,
                              void* d_out, int out_size, void* d_ws, size_t ws_size,
                              hipStream_t stream) {
    const float* h_src  = (const float*)d_in[0];
    const float* h_dst  = (const float*)d_in[1];
    const float* W      = (const float*)d_in[2];
    const float* attn_l = (const float*)d_in[3];
    const float* attn_r = (const float*)d_in[4];
    const int* src_idx  = (const int*)d_in[5];
    const int* dst_idx  = (const int*)d_in[6];

    const int n_src = in_sizes[0] / IN_FEATS;   // 50000
    const int n_dst = in_sizes[1] / IN_FEATS;   // 50000
    const int E     = in_sizes[5];              // 800000

    const int nbuck = (n_dst + 255) >> 8;       // 196 (<=256)

    // workspace layout
    char* ws = (char*)d_ws;
    size_t o = 0;
    float* v       = (float*)(ws + o); o += 4096;
    float* el      = (float*)(ws + o); o += (size_t)n_src * 4 * sizeof(float);
    float* er      = (float*)(ws + o); o += (size_t)n_dst * 4 * sizeof(float);
    int*   off     = (int*)(ws + o);   o += ((size_t)n_dst + 16) * sizeof(int);
    int*   bcnt    = (int*)(ws + o);   o += 256 * sizeof(int);
    int*   bbase   = (int*)(ws + o);   o += 260 * sizeof(int);
    int*   bcursor = (int*)(ws + o);   o += 256 * sizeof(int);
    unsigned short* Wt = (unsigned short*)(ws + o); o += (size_t)NHF * IN_FEATS * sizeof(unsigned short);
    int*   csr_src = (int*)(ws + o);   o += (size_t)E * sizeof(int);
    unsigned int* pairs = (unsigned int*)(ws + o); o += (size_t)E * sizeof(unsigned int);
    unsigned short* ft16 = (unsigned short*)(ws + o); o += (size_t)n_src * NHF * sizeof(unsigned short);

    float* out = (float*)d_out;

    prep<<<129, 256, 0, stream>>>(W, attn_r, v, Wt, bcnt);
    gemm_el<<<(n_src + 63) / 64, 256, 0, stream>>>(h_src, Wt, attn_l, ft16, el, n_src);
    compute_er<<<(n_dst + 3) / 4, 256, 0, stream>>>(h_dst, v, er, n_dst);
    bucket_hist<<<512, 256, 0, stream>>>(dst_idx, bcnt, E);
    bucket_scan<<<1, 256, 0, stream>>>(bcnt, bbase, bcursor, off, n_dst, E);
    bin_pairs<<<(E + 4095) / 4096, 256, 0, stream>>>(src_idx, dst_idx, bcursor, pairs, E);
    fine_csr<<<nbuck, 256, 0, stream>>>(pairs, bbase, off, csr_src, n_dst);
    {
        const int nwave = (n_dst + 1) >> 1;          // 2 nodes per wave
        agg_pull<<<(nwave + 3) / 4, 256, 0, stream>>>(off, csr_src, el, er,
                                                      (const uint2*)ft16, out, n_dst);
    }
}